// Round 3
// baseline (197.355 us; speedup 1.0000x reference)
//
#include <hip/hip_runtime.h>
#include <hip/hip_bf16.h>

// Problem: B=2048 pairs, D=512, K=32 features.
// out[b] = relu(x1[b]^T W[:,:,k] x2[b] + V[k].concat(x1,x2) + b[k]) @ U
// Dominant GEMM: T = x1_bf16 [2048x512] @ W_bf16 [512x16384], fused epilogue
// contracts over e (n = e*32+k) with f32 x2 into h_part[j][b][k].
// R2: staging via __builtin_amdgcn_global_load_lds width=16 (m97 pattern).
// Workspace: x1b (2MB) | Wt (16MB) | h_part (32MB) = 50MB total.

#define BATCH 2048
#define DIM 512
#define KF 32
#define NCOL (DIM * KF)      // 16384
#define JT (NCOL / 128)      // 128 column tiles

typedef __attribute__((ext_vector_type(8))) short bf16x8;
typedef __attribute__((ext_vector_type(4))) float f32x4;
typedef __attribute__((address_space(1))) const unsigned int gas_u32;
typedef __attribute__((address_space(3))) unsigned int las_u32;

static __device__ __forceinline__ ushort f2bf(float x) {
    __hip_bfloat16 h = __float2bfloat16(x);
    union { __hip_bfloat16 h; ushort u; } cv; cv.h = h;
    return cv.u;
}

// ---- x1 f32 -> bf16 ----
__global__ void cvt_x1_kernel(const float4* __restrict__ x, ushort4* __restrict__ o) {
    int i = blockIdx.x * 256 + threadIdx.x;   // 262144 float4s
    float4 v = x[i];
    ushort4 r;
    r.x = f2bf(v.x); r.y = f2bf(v.y); r.z = f2bf(v.z); r.w = f2bf(v.w);
    o[i] = r;
}

// ---- W f32 [512][16384] -> Wt bf16 [16384][512] (transpose + convert) ----
__global__ void cvt_wt_kernel(const float* __restrict__ W, ushort* __restrict__ Wt) {
    __shared__ ushort lt[64][65];             // [n_local][d_local], +1 pad
    const int n0 = blockIdx.x * 64;           // 256 blocks
    const int d0 = blockIdx.y * 64;           // 8 blocks
    const int t = threadIdx.x;
    #pragma unroll
    for (int it = 0; it < 4; ++it) {
        int q = it * 256 + t;                 // 0..1023 float4 slots
        int dl = q >> 4;                      // 0..63
        int n4 = (q & 15) * 4;                // 0..60
        float4 v = *(const float4*)&W[(size_t)(d0 + dl) * NCOL + n0 + n4];
        lt[n4 + 0][dl] = f2bf(v.x);
        lt[n4 + 1][dl] = f2bf(v.y);
        lt[n4 + 2][dl] = f2bf(v.z);
        lt[n4 + 3][dl] = f2bf(v.w);
    }
    __syncthreads();
    #pragma unroll
    for (int it = 0; it < 4; ++it) {
        int q = it * 256 + t;
        int nl = q >> 4;
        int d4 = (q & 15) * 4;
        ushort4 o;
        o.x = lt[nl][d4 + 0]; o.y = lt[nl][d4 + 1];
        o.z = lt[nl][d4 + 2]; o.w = lt[nl][d4 + 3];
        *(ushort4*)&Wt[(size_t)(n0 + nl) * DIM + d0 + d4] = o;
    }
}

// ---- fused GEMM: T-tile (128x128) + e-contraction with x2 -> h_part ----
// A = x1b [2048][512] bf16, Bt = Wt [16384][512] bf16 (i.e. W^T, rows = n)
// h_part[j][b][k] = sum_{e in tile j} T[b, e*32+k] * x2[b][e]
__global__ void gemm_fused_kernel(const ushort* __restrict__ Ab,
                                  const ushort* __restrict__ Bt,
                                  const float* __restrict__ x2,
                                  float* __restrict__ hpart) {
    __shared__ __align__(16) char smem[16384];
    ushort* As = (ushort*)smem;               // [128][32] bf16, 8KB (linear!)
    ushort* Bs = (ushort*)(smem + 8192);      // [128][32] bf16, 8KB (linear!)
    float*  hp = (float*)smem;                // [128][32] f32 epilogue reuse, 16KB

    const int j = blockIdx.x;                 // column tile 0..127
    const int i = blockIdx.y;                 // row tile 0..15
    const int t = threadIdx.x;
    const int lane = t & 63, wid = t >> 6;
    const int wr = wid >> 1, wc = wid & 1;    // wave grid 2x2, each 64x64
    const int row0 = i * 128, col0 = j * 128;
    const int l15 = lane & 15, lk = (lane >> 4) * 8, lh = lane >> 4;

    // staging geometry: thread t handles elements idx = q*2048 + t*8
    // per wave: bytes q*4096 + wid*1024 + lane*16 -> wave-uniform base + lane*16
    const int sidx0 = t * 8;
    const int sr0 = sidx0 >> 5, sc0_ = sidx0 & 31;        // q=0
    const int sidx1 = 2048 + t * 8;
    const int sr1 = sidx1 >> 5, sc1_ = sidx1 & 31;        // q=1

    f32x4 acc[4][4] = {};

    for (int kt = 0; kt < DIM; kt += 32) {
        // global -> LDS direct DMA, 16B per lane, linear LDS dest
        __builtin_amdgcn_global_load_lds(
            (gas_u32*)&Ab[(size_t)(row0 + sr0) * DIM + kt + sc0_],
            (las_u32*)&As[sidx0], 16, 0, 0);
        __builtin_amdgcn_global_load_lds(
            (gas_u32*)&Ab[(size_t)(row0 + sr1) * DIM + kt + sc1_],
            (las_u32*)&As[sidx1], 16, 0, 0);
        __builtin_amdgcn_global_load_lds(
            (gas_u32*)&Bt[(size_t)(col0 + sr0) * DIM + kt + sc0_],
            (las_u32*)&Bs[sidx0], 16, 0, 0);
        __builtin_amdgcn_global_load_lds(
            (gas_u32*)&Bt[(size_t)(col0 + sr1) * DIM + kt + sc1_],
            (las_u32*)&Bs[sidx1], 16, 0, 0);
        __syncthreads();
        bf16x8 af[4], bfr[4];
        #pragma unroll
        for (int m = 0; m < 4; ++m)
            af[m] = *(bf16x8*)&As[(wr * 64 + m * 16 + l15) * 32 + lk];
        #pragma unroll
        for (int n = 0; n < 4; ++n)
            bfr[n] = *(bf16x8*)&Bs[(wc * 64 + n * 16 + l15) * 32 + lk];
        #pragma unroll
        for (int m = 0; m < 4; ++m)
            #pragma unroll
            for (int n = 0; n < 4; ++n)
                acc[m][n] = __builtin_amdgcn_mfma_f32_16x16x32_bf16(af[m], bfr[n], acc[m][n], 0, 0, 0);
        __syncthreads();
    }

    // Epilogue: contract the 4 e-values of this tile with x2 (f32).
    // acc[m][n][reg] = T[row0 + wr*64 + m*16 + lh*4 + reg][col0 + wc*64 + n*16 + l15]
    // col -> e = col/32, kfeat = col%32. n=0/2 -> kfeat=l15, n=1/3 -> kfeat=16+l15.
    const int e0 = j * 4 + wc * 2;            // this wave covers e0, e0+1
    if (wc == 0) {
        #pragma unroll
        for (int m = 0; m < 4; ++m) {
            #pragma unroll
            for (int reg = 0; reg < 4; ++reg) {
                int row = wr * 64 + m * 16 + lh * 4 + reg;
                float xa = x2[(size_t)(row0 + row) * DIM + e0];
                float xb = x2[(size_t)(row0 + row) * DIM + e0 + 1];
                hp[row * 32 + l15]      = acc[m][0][reg] * xa + acc[m][2][reg] * xb;
                hp[row * 32 + 16 + l15] = acc[m][1][reg] * xa + acc[m][3][reg] * xb;
            }
        }
    }
    __syncthreads();
    if (wc == 1) {
        #pragma unroll
        for (int m = 0; m < 4; ++m) {
            #pragma unroll
            for (int reg = 0; reg < 4; ++reg) {
                int row = wr * 64 + m * 16 + lh * 4 + reg;
                float xa = x2[(size_t)(row0 + row) * DIM + e0];
                float xb = x2[(size_t)(row0 + row) * DIM + e0 + 1];
                hp[row * 32 + l15]      += acc[m][0][reg] * xa + acc[m][2][reg] * xb;
                hp[row * 32 + 16 + l15] += acc[m][1][reg] * xa + acc[m][3][reg] * xb;
            }
        }
    }
    __syncthreads();
    // write h_part[j][row0+row][kfeat], 4096 floats, coalesced float4
    #pragma unroll
    for (int q = 0; q < 4; ++q) {
        int idx = q * 1024 + t * 4;
        int row = idx >> 5, kf = idx & 31;
        *(float4*)&hpart[((size_t)j * BATCH + row0 + row) * KF + kf] = *(float4*)&hp[idx];
    }
}

// ---- final: sum h_part over j, add V-linear term + bias, relu, dot U ----
__global__ void reduce_out_kernel(const float* __restrict__ hpart,
                                  const float* __restrict__ x1,
                                  const float* __restrict__ x2,
                                  const float* __restrict__ V,
                                  const float* __restrict__ U,
                                  const float* __restrict__ bias,
                                  float* __restrict__ out) {
    const int b = blockIdx.x;
    const int t = threadIdx.x;
    __shared__ float red[256];
    __shared__ float hred[8][32];

    // V-linear term: v_out[b][k] = concat(x1[b],x2[b]) . V[k]  (f32)
    const int k = t >> 3, sub = t & 7;
    const float* xrow = (sub < 4) ? (x1 + (size_t)b * DIM) : (x2 + (size_t)b * DIM);
    const int dbase = (sub & 3) * 128;
    const float* vrow = V + (size_t)k * (2 * DIM) + sub * 128;
    float vsum = 0.0f;
    #pragma unroll 8
    for (int d = 0; d < 128; d += 4) {
        float4 xv = *(const float4*)&xrow[dbase + d];
        float4 vv = *(const float4*)&vrow[d];
        vsum += xv.x * vv.x + xv.y * vv.y + xv.z * vv.z + xv.w * vv.w;
    }
    red[t] = vsum;

    // h sum over j: thread t: kf = t&31, jg = t>>5 handles j = jg, jg+8, ...
    const int kf = t & 31, jg = t >> 5;
    float hsum = 0.0f;
    for (int jj = jg; jj < JT; jj += 8)
        hsum += hpart[((size_t)jj * BATCH + b) * KF + kf];
    hred[jg][kf] = hsum;
    __syncthreads();

    float val = 0.0f;
    if (t < 32) {
        float hs = 0.0f;
        #pragma unroll
        for (int g = 0; g < 8; ++g) hs += hred[g][t];
        float vo = 0.0f;
        #pragma unroll
        for (int s = 0; s < 8; ++s) vo += red[t * 8 + s];
        float sc = hs + vo + bias[t];
        sc = fmaxf(sc, 0.0f);
        val = sc * U[t];
    }
    if (t < 64) {
        #pragma unroll
        for (int off = 16; off; off >>= 1) val += __shfl_down(val, off);
        if (t == 0) out[b] = val;
    }
}

extern "C" void kernel_launch(void* const* d_in, const int* in_sizes, int n_in,
                              void* d_out, int out_size, void* d_ws, size_t ws_size,
                              hipStream_t stream) {
    const float* x1   = (const float*)d_in[0];   // [2048][512]
    const float* x2   = (const float*)d_in[1];   // [2048][512]
    const float* W    = (const float*)d_in[2];   // [512][512][32]
    const float* V    = (const float*)d_in[3];   // [32][1024]
    const float* U    = (const float*)d_in[4];   // [32][1]
    const float* bias = (const float*)d_in[5];   // [32]
    float* out = (float*)d_out;                  // [2048]

    char* ws = (char*)d_ws;
    ushort* x1b = (ushort*)ws;                                   // 2 MB
    ushort* Wt  = (ushort*)(ws + (size_t)2 * 1024 * 1024);       // 16 MB
    float*  hp  = (float*)(ws + (size_t)18 * 1024 * 1024);       // 32 MB

    cvt_x1_kernel<<<dim3(1024), dim3(256), 0, stream>>>((const float4*)x1, (ushort4*)x1b);
    cvt_wt_kernel<<<dim3(256, 8), dim3(256), 0, stream>>>(W, Wt);
    gemm_fused_kernel<<<dim3(JT, 16), dim3(256), 0, stream>>>(x1b, Wt, x2, hp);
    reduce_out_kernel<<<dim3(BATCH), dim3(256), 0, stream>>>(hp, x1, x2, V, U, bias, out);
}

// Round 6
// 193.379 us; speedup vs baseline: 1.0206x; 1.0206x over previous
//
#include <hip/hip_runtime.h>
#include <hip/hip_bf16.h>

// Problem: B=2048 pairs, D=512, K=32 features.
// out[b] = relu(x1[b]^T W[:,:,k] x2[b] + V[k].concat(x1,x2) + b[k]) @ U
// Dominant GEMM: T = x1_bf16 [2048x512] @ W_bf16 [512x16384], fused epilogue
// contracts over e (n = e*32+k) with f32 x2 into h_part[b][j][k].
// R2: staging via __builtin_amdgcn_global_load_lds width=16 (m97 pattern).
// R3: hpart layout [j][b][k] -> [b][j][k]; reduce_out was 68us @ 312GB/s
//     (latency-bound 128B segments strided 2MB). Now fully coalesced.
// R4/R5: resubmit (broker timeouts; R3 fix never measured). All candidate
//     bundles predicted-null (dbuf m99/m100) or high-risk blind (8-phase).
// Workspace: x1b (2MB) | Wt (16MB) | h_part (32MB) = 50MB total.

#define BATCH 2048
#define DIM 512
#define KF 32
#define NCOL (DIM * KF)      // 16384
#define JT (NCOL / 128)      // 128 column tiles

typedef __attribute__((ext_vector_type(8))) short bf16x8;
typedef __attribute__((ext_vector_type(4))) float f32x4;
typedef __attribute__((address_space(1))) const unsigned int gas_u32;
typedef __attribute__((address_space(3))) unsigned int las_u32;

static __device__ __forceinline__ ushort f2bf(float x) {
    __hip_bfloat16 h = __float2bfloat16(x);
    union { __hip_bfloat16 h; ushort u; } cv; cv.h = h;
    return cv.u;
}

// ---- x1 f32 -> bf16 ----
__global__ void cvt_x1_kernel(const float4* __restrict__ x, ushort4* __restrict__ o) {
    int i = blockIdx.x * 256 + threadIdx.x;   // 262144 float4s
    float4 v = x[i];
    ushort4 r;
    r.x = f2bf(v.x); r.y = f2bf(v.y); r.z = f2bf(v.z); r.w = f2bf(v.w);
    o[i] = r;
}

// ---- W f32 [512][16384] -> Wt bf16 [16384][512] (transpose + convert) ----
__global__ void cvt_wt_kernel(const float* __restrict__ W, ushort* __restrict__ Wt) {
    __shared__ ushort lt[64][65];             // [n_local][d_local], +1 pad
    const int n0 = blockIdx.x * 64;           // 256 blocks
    const int d0 = blockIdx.y * 64;           // 8 blocks
    const int t = threadIdx.x;
    #pragma unroll
    for (int it = 0; it < 4; ++it) {
        int q = it * 256 + t;                 // 0..1023 float4 slots
        int dl = q >> 4;                      // 0..63
        int n4 = (q & 15) * 4;                // 0..60
        float4 v = *(const float4*)&W[(size_t)(d0 + dl) * NCOL + n0 + n4];
        lt[n4 + 0][dl] = f2bf(v.x);
        lt[n4 + 1][dl] = f2bf(v.y);
        lt[n4 + 2][dl] = f2bf(v.z);
        lt[n4 + 3][dl] = f2bf(v.w);
    }
    __syncthreads();
    #pragma unroll
    for (int it = 0; it < 4; ++it) {
        int q = it * 256 + t;
        int nl = q >> 4;
        int d4 = (q & 15) * 4;
        ushort4 o;
        o.x = lt[nl][d4 + 0]; o.y = lt[nl][d4 + 1];
        o.z = lt[nl][d4 + 2]; o.w = lt[nl][d4 + 3];
        *(ushort4*)&Wt[(size_t)(n0 + nl) * DIM + d0 + d4] = o;
    }
}

// ---- fused GEMM: T-tile (128x128) + e-contraction with x2 -> h_part ----
// A = x1b [2048][512] bf16, Bt = Wt [16384][512] bf16 (i.e. W^T, rows = n)
// h_part[b][j][k] = sum_{e in tile j} T[b, e*32+k] * x2[b][e]
__global__ void gemm_fused_kernel(const ushort* __restrict__ Ab,
                                  const ushort* __restrict__ Bt,
                                  const float* __restrict__ x2,
                                  float* __restrict__ hpart) {
    __shared__ __align__(16) char smem[16384];
    ushort* As = (ushort*)smem;               // [128][32] bf16, 8KB (linear!)
    ushort* Bs = (ushort*)(smem + 8192);      // [128][32] bf16, 8KB (linear!)
    float*  hp = (float*)smem;                // [128][32] f32 epilogue reuse, 16KB

    const int j = blockIdx.x;                 // column tile 0..127
    const int i = blockIdx.y;                 // row tile 0..15
    const int t = threadIdx.x;
    const int lane = t & 63, wid = t >> 6;
    const int wr = wid >> 1, wc = wid & 1;    // wave grid 2x2, each 64x64
    const int row0 = i * 128, col0 = j * 128;
    const int l15 = lane & 15, lk = (lane >> 4) * 8, lh = lane >> 4;

    // staging geometry: thread t handles elements idx = q*2048 + t*8
    // per wave: bytes q*4096 + wid*1024 + lane*16 -> wave-uniform base + lane*16
    const int sidx0 = t * 8;
    const int sr0 = sidx0 >> 5, sc0_ = sidx0 & 31;        // q=0
    const int sidx1 = 2048 + t * 8;
    const int sr1 = sidx1 >> 5, sc1_ = sidx1 & 31;        // q=1

    f32x4 acc[4][4] = {};

    for (int kt = 0; kt < DIM; kt += 32) {
        // global -> LDS direct DMA, 16B per lane, linear LDS dest
        __builtin_amdgcn_global_load_lds(
            (gas_u32*)&Ab[(size_t)(row0 + sr0) * DIM + kt + sc0_],
            (las_u32*)&As[sidx0], 16, 0, 0);
        __builtin_amdgcn_global_load_lds(
            (gas_u32*)&Ab[(size_t)(row0 + sr1) * DIM + kt + sc1_],
            (las_u32*)&As[sidx1], 16, 0, 0);
        __builtin_amdgcn_global_load_lds(
            (gas_u32*)&Bt[(size_t)(col0 + sr0) * DIM + kt + sc0_],
            (las_u32*)&Bs[sidx0], 16, 0, 0);
        __builtin_amdgcn_global_load_lds(
            (gas_u32*)&Bt[(size_t)(col0 + sr1) * DIM + kt + sc1_],
            (las_u32*)&Bs[sidx1], 16, 0, 0);
        __syncthreads();
        bf16x8 af[4], bfr[4];
        #pragma unroll
        for (int m = 0; m < 4; ++m)
            af[m] = *(bf16x8*)&As[(wr * 64 + m * 16 + l15) * 32 + lk];
        #pragma unroll
        for (int n = 0; n < 4; ++n)
            bfr[n] = *(bf16x8*)&Bs[(wc * 64 + n * 16 + l15) * 32 + lk];
        #pragma unroll
        for (int m = 0; m < 4; ++m)
            #pragma unroll
            for (int n = 0; n < 4; ++n)
                acc[m][n] = __builtin_amdgcn_mfma_f32_16x16x32_bf16(af[m], bfr[n], acc[m][n], 0, 0, 0);
        __syncthreads();
    }

    // Epilogue: contract the 4 e-values of this tile with x2 (f32).
    // acc[m][n][reg] = T[row0 + wr*64 + m*16 + lh*4 + reg][col0 + wc*64 + n*16 + l15]
    // col -> e = col/32, kfeat = col%32. n=0/2 -> kfeat=l15, n=1/3 -> kfeat=16+l15.
    const int e0 = j * 4 + wc * 2;            // this wave covers e0, e0+1
    if (wc == 0) {
        #pragma unroll
        for (int m = 0; m < 4; ++m) {
            #pragma unroll
            for (int reg = 0; reg < 4; ++reg) {
                int row = wr * 64 + m * 16 + lh * 4 + reg;
                float xa = x2[(size_t)(row0 + row) * DIM + e0];
                float xb = x2[(size_t)(row0 + row) * DIM + e0 + 1];
                hp[row * 32 + l15]      = acc[m][0][reg] * xa + acc[m][2][reg] * xb;
                hp[row * 32 + 16 + l15] = acc[m][1][reg] * xa + acc[m][3][reg] * xb;
            }
        }
    }
    __syncthreads();
    if (wc == 1) {
        #pragma unroll
        for (int m = 0; m < 4; ++m) {
            #pragma unroll
            for (int reg = 0; reg < 4; ++reg) {
                int row = wr * 64 + m * 16 + lh * 4 + reg;
                float xa = x2[(size_t)(row0 + row) * DIM + e0];
                float xb = x2[(size_t)(row0 + row) * DIM + e0 + 1];
                hp[row * 32 + l15]      += acc[m][0][reg] * xa + acc[m][2][reg] * xb;
                hp[row * 32 + 16 + l15] += acc[m][1][reg] * xa + acc[m][3][reg] * xb;
            }
        }
    }
    __syncthreads();
    // write h_part[b = row0+row][j][kfeat] -- 128B segments per 8 lanes,
    // 16KB row stride; reduce-side reads are fully contiguous per b.
    #pragma unroll
    for (int q = 0; q < 4; ++q) {
        int idx = q * 1024 + t * 4;
        int row = idx >> 5, kf = idx & 31;
        *(float4*)&hpart[(size_t)(row0 + row) * (JT * KF) + j * KF + kf] = *(float4*)&hp[idx];
    }
}

// ---- final: sum h_part[b][*][*] over j, add V-linear + bias, relu, dot U ----
__global__ void reduce_out_kernel(const float* __restrict__ hpart,
                                  const float* __restrict__ x1,
                                  const float* __restrict__ x2,
                                  const float* __restrict__ V,
                                  const float* __restrict__ U,
                                  const float* __restrict__ bias,
                                  float* __restrict__ out) {
    const int b = blockIdx.x;
    const int t = threadIdx.x;
    __shared__ float red[256];
    __shared__ float4 hsm[256];
    __shared__ float hk[32];

    // V-linear term: v_out[b][k] = concat(x1[b],x2[b]) . V[k]  (f32)
    const int k = t >> 3, sub = t & 7;
    const float* xrow = (sub < 4) ? (x1 + (size_t)b * DIM) : (x2 + (size_t)b * DIM);
    const int dbase = (sub & 3) * 128;
    const float* vrow = V + (size_t)k * (2 * DIM) + sub * 128;
    float vsum = 0.0f;
    #pragma unroll 8
    for (int d = 0; d < 128; d += 4) {
        float4 xv = *(const float4*)&xrow[dbase + d];
        float4 vv = *(const float4*)&vrow[d];
        vsum += xv.x * vv.x + xv.y * vv.y + xv.z * vv.z + xv.w * vv.w;
    }
    red[t] = vsum;

    // h sum over j: contiguous 16KB row hpart[b][0..127][0..31], float4 loads.
    // element offset off = p*1024 + t*4: j = p*32 + (t>>3), kquad = (t&7)*4
    const float* hb = hpart + (size_t)b * (JT * KF);
    float4 a4 = {0.f, 0.f, 0.f, 0.f};
    #pragma unroll
    for (int p = 0; p < 4; ++p) {
        float4 v = *(const float4*)&hb[p * 1024 + t * 4];
        a4.x += v.x; a4.y += v.y; a4.z += v.z; a4.w += v.w;
    }
    hsm[t] = a4;   // hsm[(jgroup=t>>3)*8 + (kquad=t&7)]
    __syncthreads();
    if (t < 8) {
        float4 s = {0.f, 0.f, 0.f, 0.f};
        #pragma unroll
        for (int g = 0; g < 32; ++g) {
            float4 v = hsm[g * 8 + t];
            s.x += v.x; s.y += v.y; s.z += v.z; s.w += v.w;
        }
        hk[t * 4 + 0] = s.x; hk[t * 4 + 1] = s.y;
        hk[t * 4 + 2] = s.z; hk[t * 4 + 3] = s.w;
    }
    __syncthreads();

    float val = 0.0f;
    if (t < 32) {
        float vo = 0.0f;
        #pragma unroll
        for (int s = 0; s < 8; ++s) vo += red[t * 8 + s];
        float sc = hk[t] + vo + bias[t];
        sc = fmaxf(sc, 0.0f);
        val = sc * U[t];
    }
    if (t < 64) {
        #pragma unroll
        for (int off = 16; off; off >>= 1) val += __shfl_down(val, off);
        if (t == 0) out[b] = val;
    }
}

extern "C" void kernel_launch(void* const* d_in, const int* in_sizes, int n_in,
                              void* d_out, int out_size, void* d_ws, size_t ws_size,
                              hipStream_t stream) {
    const float* x1   = (const float*)d_in[0];   // [2048][512]
    const float* x2   = (const float*)d_in[1];   // [2048][512]
    const float* W    = (const float*)d_in[2];   // [512][512][32]
    const float* V    = (const float*)d_in[3];   // [32][1024]
    const float* U    = (const float*)d_in[4];   // [32][1]
    const float* bias = (const float*)d_in[5];   // [32]
    float* out = (float*)d_out;                  // [2048]

    char* ws = (char*)d_ws;
    ushort* x1b = (ushort*)ws;                                   // 2 MB
    ushort* Wt  = (ushort*)(ws + (size_t)2 * 1024 * 1024);       // 16 MB
    float*  hp  = (float*)(ws + (size_t)18 * 1024 * 1024);       // 32 MB

    cvt_x1_kernel<<<dim3(1024), dim3(256), 0, stream>>>((const float4*)x1, (ushort4*)x1b);
    cvt_wt_kernel<<<dim3(256, 8), dim3(256), 0, stream>>>(W, Wt);
    gemm_fused_kernel<<<dim3(JT, 16), dim3(256), 0, stream>>>(x1b, Wt, x2, hp);
    reduce_out_kernel<<<dim3(BATCH), dim3(256), 0, stream>>>(hp, x1, x2, V, U, bias, out);
}

// Round 7
// 174.958 us; speedup vs baseline: 1.1280x; 1.1053x over previous
//
#include <hip/hip_runtime.h>
#include <hip/hip_bf16.h>

// Problem: B=2048 pairs, D=512, K=32 features.
// out[b] = relu(x1[b]^T W[:,:,k] x2[b] + V[k].concat(x1,x2) + b[k]) @ U
// Dominant GEMM: T = x1_bf16 [2048x512] @ W_bf16 [512x16384], fused epilogue
// contracts over e (n = e*32+k) with f32 x2 into h_part[b][j][k].
// R2: staging via __builtin_amdgcn_global_load_lds width=16 (m97 pattern).
// R3: hpart [j][b][k] -> [b][j][k]. R6 RESULT: reduce_out UNCHANGED at 68us
//     -> hpart pattern was NOT the bottleneck. Real culprit: per-block V-term
//     gather (64 distinct 16B segments/instr, 512B lane stride; 256MB of
//     L1-serialized V re-reads grid-wide; VALUBusy 5%, MfmaUtil 0).
// R6 fix: dedicated vout_kernel (computes V-term once, coalesced, LDS-staged
//     x rows, wave shuffle-reduce); reduce_out drops the V gather entirely.
// Workspace: x1b (2MB) | Wt (16MB) | h_part (32MB) | vout (256KB).

#define BATCH 2048
#define DIM 512
#define KF 32
#define NCOL (DIM * KF)      // 16384
#define JT (NCOL / 128)      // 128 column tiles

typedef __attribute__((ext_vector_type(8))) short bf16x8;
typedef __attribute__((ext_vector_type(4))) float f32x4;
typedef __attribute__((address_space(1))) const unsigned int gas_u32;
typedef __attribute__((address_space(3))) unsigned int las_u32;

static __device__ __forceinline__ ushort f2bf(float x) {
    __hip_bfloat16 h = __float2bfloat16(x);
    union { __hip_bfloat16 h; ushort u; } cv; cv.h = h;
    return cv.u;
}

// ---- x1 f32 -> bf16 ----
__global__ void cvt_x1_kernel(const float4* __restrict__ x, ushort4* __restrict__ o) {
    int i = blockIdx.x * 256 + threadIdx.x;   // 262144 float4s
    float4 v = x[i];
    ushort4 r;
    r.x = f2bf(v.x); r.y = f2bf(v.y); r.z = f2bf(v.z); r.w = f2bf(v.w);
    o[i] = r;
}

// ---- W f32 [512][16384] -> Wt bf16 [16384][512] (transpose + convert) ----
__global__ void cvt_wt_kernel(const float* __restrict__ W, ushort* __restrict__ Wt) {
    __shared__ ushort lt[64][65];             // [n_local][d_local], +1 pad
    const int n0 = blockIdx.x * 64;           // 256 blocks
    const int d0 = blockIdx.y * 64;           // 8 blocks
    const int t = threadIdx.x;
    #pragma unroll
    for (int it = 0; it < 4; ++it) {
        int q = it * 256 + t;                 // 0..1023 float4 slots
        int dl = q >> 4;                      // 0..63
        int n4 = (q & 15) * 4;                // 0..60
        float4 v = *(const float4*)&W[(size_t)(d0 + dl) * NCOL + n0 + n4];
        lt[n4 + 0][dl] = f2bf(v.x);
        lt[n4 + 1][dl] = f2bf(v.y);
        lt[n4 + 2][dl] = f2bf(v.z);
        lt[n4 + 3][dl] = f2bf(v.w);
    }
    __syncthreads();
    #pragma unroll
    for (int it = 0; it < 4; ++it) {
        int q = it * 256 + t;
        int nl = q >> 4;
        int d4 = (q & 15) * 4;
        ushort4 o;
        o.x = lt[nl][d4 + 0]; o.y = lt[nl][d4 + 1];
        o.z = lt[nl][d4 + 2]; o.w = lt[nl][d4 + 3];
        *(ushort4*)&Wt[(size_t)(n0 + nl) * DIM + d0 + d4] = o;
    }
}

// ---- V-linear term, computed ONCE, coalesced ----
// vout[b][k] = concat(x1[b], x2[b]) . V[k]
__global__ void vout_kernel(const float* __restrict__ x1,
                            const float* __restrict__ x2,
                            const float* __restrict__ V,
                            float* __restrict__ vout) {
    __shared__ float xs[8][1024];             // 32KB: 8 concat rows
    const int b0 = blockIdx.x * 8;            // 256 blocks
    const int t = threadIdx.x;
    #pragma unroll
    for (int it = 0; it < 4; ++it) {
        int q = it * 256 + t;                 // 0..1023 float4 slots
        int r = q >> 7;                       // 0..7
        int c = (q & 127) * 4;                // 0..508
        *(float4*)&xs[r][c]       = *(const float4*)&x1[(size_t)(b0 + r) * DIM + c];
        *(float4*)&xs[r][512 + c] = *(const float4*)&x2[(size_t)(b0 + r) * DIM + c];
    }
    __syncthreads();
    const int lane = t & 63, w = t >> 6;      // wave w handles rows 2w, 2w+1
    #pragma unroll
    for (int rr = 0; rr < 2; ++rr) {
        const int r = w * 2 + rr;
        for (int k = 0; k < KF; ++k) {
            const float* vrow = V + (size_t)k * 1024;
            float s = 0.0f;
            #pragma unroll
            for (int i = 0; i < 4; ++i) {     // lane-coalesced float4 over V row
                float4 vv = *(const float4*)&vrow[i * 256 + lane * 4];
                float4 xv = *(const float4*)&xs[r][i * 256 + lane * 4];
                s += vv.x * xv.x + vv.y * xv.y + vv.z * xv.z + vv.w * xv.w;
            }
            #pragma unroll
            for (int off = 32; off; off >>= 1) s += __shfl_down(s, off);
            if (lane == 0) vout[(size_t)(b0 + r) * KF + k] = s;
        }
    }
}

// ---- fused GEMM: T-tile (128x128) + e-contraction with x2 -> h_part ----
// A = x1b [2048][512] bf16, Bt = Wt [16384][512] bf16 (i.e. W^T, rows = n)
// h_part[b][j][k] = sum_{e in tile j} T[b, e*32+k] * x2[b][e]
__global__ void gemm_fused_kernel(const ushort* __restrict__ Ab,
                                  const ushort* __restrict__ Bt,
                                  const float* __restrict__ x2,
                                  float* __restrict__ hpart) {
    __shared__ __align__(16) char smem[16384];
    ushort* As = (ushort*)smem;               // [128][32] bf16, 8KB (linear!)
    ushort* Bs = (ushort*)(smem + 8192);      // [128][32] bf16, 8KB (linear!)
    float*  hp = (float*)smem;                // [128][32] f32 epilogue reuse, 16KB

    const int j = blockIdx.x;                 // column tile 0..127
    const int i = blockIdx.y;                 // row tile 0..15
    const int t = threadIdx.x;
    const int lane = t & 63, wid = t >> 6;
    const int wr = wid >> 1, wc = wid & 1;    // wave grid 2x2, each 64x64
    const int row0 = i * 128, col0 = j * 128;
    const int l15 = lane & 15, lk = (lane >> 4) * 8, lh = lane >> 4;

    // staging geometry: thread t handles elements idx = q*2048 + t*8
    // per wave: bytes q*4096 + wid*1024 + lane*16 -> wave-uniform base + lane*16
    const int sidx0 = t * 8;
    const int sr0 = sidx0 >> 5, sc0_ = sidx0 & 31;        // q=0
    const int sidx1 = 2048 + t * 8;
    const int sr1 = sidx1 >> 5, sc1_ = sidx1 & 31;        // q=1

    f32x4 acc[4][4] = {};

    for (int kt = 0; kt < DIM; kt += 32) {
        // global -> LDS direct DMA, 16B per lane, linear LDS dest
        __builtin_amdgcn_global_load_lds(
            (gas_u32*)&Ab[(size_t)(row0 + sr0) * DIM + kt + sc0_],
            (las_u32*)&As[sidx0], 16, 0, 0);
        __builtin_amdgcn_global_load_lds(
            (gas_u32*)&Ab[(size_t)(row0 + sr1) * DIM + kt + sc1_],
            (las_u32*)&As[sidx1], 16, 0, 0);
        __builtin_amdgcn_global_load_lds(
            (gas_u32*)&Bt[(size_t)(col0 + sr0) * DIM + kt + sc0_],
            (las_u32*)&Bs[sidx0], 16, 0, 0);
        __builtin_amdgcn_global_load_lds(
            (gas_u32*)&Bt[(size_t)(col0 + sr1) * DIM + kt + sc1_],
            (las_u32*)&Bs[sidx1], 16, 0, 0);
        __syncthreads();
        bf16x8 af[4], bfr[4];
        #pragma unroll
        for (int m = 0; m < 4; ++m)
            af[m] = *(bf16x8*)&As[(wr * 64 + m * 16 + l15) * 32 + lk];
        #pragma unroll
        for (int n = 0; n < 4; ++n)
            bfr[n] = *(bf16x8*)&Bs[(wc * 64 + n * 16 + l15) * 32 + lk];
        #pragma unroll
        for (int m = 0; m < 4; ++m)
            #pragma unroll
            for (int n = 0; n < 4; ++n)
                acc[m][n] = __builtin_amdgcn_mfma_f32_16x16x32_bf16(af[m], bfr[n], acc[m][n], 0, 0, 0);
        __syncthreads();
    }

    // Epilogue: contract the 4 e-values of this tile with x2 (f32).
    // acc[m][n][reg] = T[row0 + wr*64 + m*16 + lh*4 + reg][col0 + wc*64 + n*16 + l15]
    // col -> e = col/32, kfeat = col%32. n=0/2 -> kfeat=l15, n=1/3 -> kfeat=16+l15.
    const int e0 = j * 4 + wc * 2;            // this wave covers e0, e0+1
    if (wc == 0) {
        #pragma unroll
        for (int m = 0; m < 4; ++m) {
            #pragma unroll
            for (int reg = 0; reg < 4; ++reg) {
                int row = wr * 64 + m * 16 + lh * 4 + reg;
                float xa = x2[(size_t)(row0 + row) * DIM + e0];
                float xb = x2[(size_t)(row0 + row) * DIM + e0 + 1];
                hp[row * 32 + l15]      = acc[m][0][reg] * xa + acc[m][2][reg] * xb;
                hp[row * 32 + 16 + l15] = acc[m][1][reg] * xa + acc[m][3][reg] * xb;
            }
        }
    }
    __syncthreads();
    if (wc == 1) {
        #pragma unroll
        for (int m = 0; m < 4; ++m) {
            #pragma unroll
            for (int reg = 0; reg < 4; ++reg) {
                int row = wr * 64 + m * 16 + lh * 4 + reg;
                float xa = x2[(size_t)(row0 + row) * DIM + e0];
                float xb = x2[(size_t)(row0 + row) * DIM + e0 + 1];
                hp[row * 32 + l15]      += acc[m][0][reg] * xa + acc[m][2][reg] * xb;
                hp[row * 32 + 16 + l15] += acc[m][1][reg] * xa + acc[m][3][reg] * xb;
            }
        }
    }
    __syncthreads();
    // write h_part[b = row0+row][j][kfeat]
    #pragma unroll
    for (int q = 0; q < 4; ++q) {
        int idx = q * 1024 + t * 4;
        int row = idx >> 5, kf = idx & 31;
        *(float4*)&hpart[(size_t)(row0 + row) * (JT * KF) + j * KF + kf] = *(float4*)&hp[idx];
    }
}

// ---- final: sum h_part[b][*][*] over j, + vout + bias, relu, dot U ----
__global__ void reduce_out_kernel(const float* __restrict__ hpart,
                                  const float* __restrict__ vout,
                                  const float* __restrict__ U,
                                  const float* __restrict__ bias,
                                  float* __restrict__ out) {
    const int b = blockIdx.x;
    const int t = threadIdx.x;
    __shared__ float4 hsm[256];
    __shared__ float hk[32];

    // h sum over j: contiguous 16KB row hpart[b][0..127][0..31], float4 loads.
    const float* hb = hpart + (size_t)b * (JT * KF);
    float4 a4 = {0.f, 0.f, 0.f, 0.f};
    #pragma unroll
    for (int p = 0; p < 4; ++p) {
        float4 v = *(const float4*)&hb[p * 1024 + t * 4];
        a4.x += v.x; a4.y += v.y; a4.z += v.z; a4.w += v.w;
    }
    hsm[t] = a4;   // hsm[(jgroup=t>>3)*8 + (kquad=t&7)]
    __syncthreads();
    if (t < 8) {
        float4 s = {0.f, 0.f, 0.f, 0.f};
        #pragma unroll
        for (int g = 0; g < 32; ++g) {
            float4 v = hsm[g * 8 + t];
            s.x += v.x; s.y += v.y; s.z += v.z; s.w += v.w;
        }
        hk[t * 4 + 0] = s.x; hk[t * 4 + 1] = s.y;
        hk[t * 4 + 2] = s.z; hk[t * 4 + 3] = s.w;
    }
    __syncthreads();

    float val = 0.0f;
    if (t < 32) {
        float sc = hk[t] + vout[(size_t)b * KF + t] + bias[t];
        sc = fmaxf(sc, 0.0f);
        val = sc * U[t];
    }
    if (t < 64) {
        #pragma unroll
        for (int off = 16; off; off >>= 1) val += __shfl_down(val, off);
        if (t == 0) out[b] = val;
    }
}

extern "C" void kernel_launch(void* const* d_in, const int* in_sizes, int n_in,
                              void* d_out, int out_size, void* d_ws, size_t ws_size,
                              hipStream_t stream) {
    const float* x1   = (const float*)d_in[0];   // [2048][512]
    const float* x2   = (const float*)d_in[1];   // [2048][512]
    const float* W    = (const float*)d_in[2];   // [512][512][32]
    const float* V    = (const float*)d_in[3];   // [32][1024]
    const float* U    = (const float*)d_in[4];   // [32][1]
    const float* bias = (const float*)d_in[5];   // [32]
    float* out = (float*)d_out;                  // [2048]

    char* ws = (char*)d_ws;
    ushort* x1b = (ushort*)ws;                                   // 2 MB
    ushort* Wt  = (ushort*)(ws + (size_t)2 * 1024 * 1024);       // 16 MB
    float*  hp  = (float*)(ws + (size_t)18 * 1024 * 1024);       // 32 MB
    float*  vo  = (float*)(ws + (size_t)50 * 1024 * 1024);       // 256 KB

    cvt_x1_kernel<<<dim3(1024), dim3(256), 0, stream>>>((const float4*)x1, (ushort4*)x1b);
    cvt_wt_kernel<<<dim3(256, 8), dim3(256), 0, stream>>>(W, Wt);
    vout_kernel<<<dim3(BATCH / 8), dim3(256), 0, stream>>>(x1, x2, V, vo);
    gemm_fused_kernel<<<dim3(JT, 16), dim3(256), 0, stream>>>(x1b, Wt, x2, hp);
    reduce_out_kernel<<<dim3(BATCH), dim3(256), 0, stream>>>(hp, vo, U, bias, out);
}

// Round 10
// 155.628 us; speedup vs baseline: 1.2681x; 1.1242x over previous
//
#include <hip/hip_runtime.h>
#include <hip/hip_bf16.h>

// Problem: B=2048 pairs, D=512, K=32 features.
// out[b] = relu(x1[b]^T W[:,:,k] x2[b] + V[k].concat(x1,x2) + b[k]) @ U
// Dominant GEMM: T = x1_bf16 [2048x512] @ W_bf16 [512x16384], fused epilogue
// contracts over e (n = e*32+k) with f32 x2 into h_part[b][j][k].
// R2: global_load_lds width=16 staging (m97). R6: vout extracted (V-gather
//     was 68us). R7: 175us, gemm top @51us, BANK_CONFLICT 4.98M.
// R8: both-sides XOR swizzle (rule #21): source chunk c ^= (r&6)>>1, read col
//     lk ^= (l15&6)<<2. + vout k-unroll x4 (was serial-latency-bound).
// R9: fuse {vout, cvt_x1, cvt_wt} into ONE dispatch (blockIdx ranges):
//     latency-bound vout overlaps BW-bound cvt_wt instead of serializing;
//     R6->R7 delta accounting says ~40-50us hides in these middle ranks.
// Workspace: x1b (2MB) | Wt (16MB) | h_part (32MB) | vout (256KB).

#define BATCH 2048
#define DIM 512
#define KF 32
#define NCOL (DIM * KF)      // 16384
#define JT (NCOL / 128)      // 128 column tiles

typedef __attribute__((ext_vector_type(8))) short bf16x8;
typedef __attribute__((ext_vector_type(4))) float f32x4;
typedef __attribute__((address_space(1))) const unsigned int gas_u32;
typedef __attribute__((address_space(3))) unsigned int las_u32;

static __device__ __forceinline__ ushort f2bf(float x) {
    __hip_bfloat16 h = __float2bfloat16(x);
    union { __hip_bfloat16 h; ushort u; } cv; cv.h = h;
    return cv.u;
}

// ---- fused prep: vout [0,256) | cvt_x1 [256,1280) | cvt_wt [1280,3328) ----
__global__ void fused_prep_kernel(const float* __restrict__ x1,
                                  const float* __restrict__ x2,
                                  const float* __restrict__ W,
                                  const float* __restrict__ V,
                                  ushort* __restrict__ x1b,
                                  ushort* __restrict__ Wt,
                                  float* __restrict__ vout) {
    __shared__ __align__(16) char sbuf[32768];
    const int bx = blockIdx.x;
    const int t = threadIdx.x;

    if (bx < 256) {
        // ---- vout: vout[b][k] = concat(x1[b],x2[b]) . V[k], k-unrolled x4 ----
        float (*xs)[1024] = (float(*)[1024])sbuf;   // 8 rows x 1024
        const int b0 = bx * 8;
        #pragma unroll
        for (int it = 0; it < 4; ++it) {
            int q = it * 256 + t;
            int r = q >> 7;
            int c = (q & 127) * 4;
            *(float4*)&xs[r][c]       = *(const float4*)&x1[(size_t)(b0 + r) * DIM + c];
            *(float4*)&xs[r][512 + c] = *(const float4*)&x2[(size_t)(b0 + r) * DIM + c];
        }
        __syncthreads();
        const int lane = t & 63, w = t >> 6;        // wave w: rows 2w, 2w+1
        #pragma unroll
        for (int rr = 0; rr < 2; ++rr) {
            const int r = w * 2 + rr;
            float4 xv[4];
            #pragma unroll
            for (int i = 0; i < 4; ++i)
                xv[i] = *(const float4*)&xs[r][i * 256 + lane * 4];
            #pragma unroll
            for (int k0 = 0; k0 < KF; k0 += 4) {
                float s[4] = {0.f, 0.f, 0.f, 0.f};
                #pragma unroll
                for (int kk = 0; kk < 4; ++kk) {
                    const float* vrow = V + (size_t)(k0 + kk) * 1024;
                    #pragma unroll
                    for (int i = 0; i < 4; ++i) {
                        float4 vv = *(const float4*)&vrow[i * 256 + lane * 4];
                        s[kk] += vv.x * xv[i].x + vv.y * xv[i].y + vv.z * xv[i].z + vv.w * xv[i].w;
                    }
                }
                #pragma unroll
                for (int kk = 0; kk < 4; ++kk) {
                    float v = s[kk];
                    #pragma unroll
                    for (int off = 32; off; off >>= 1) v += __shfl_down(v, off);
                    if (lane == 0) vout[(size_t)(b0 + r) * KF + k0 + kk] = v;
                }
            }
        }
    } else if (bx < 1280) {
        // ---- cvt_x1: f32 -> bf16, 1024 blocks ----
        int i = (bx - 256) * 256 + t;               // 262144 float4 slots
        float4 v = *((const float4*)x1 + i);
        ushort4 r;
        r.x = f2bf(v.x); r.y = f2bf(v.y); r.z = f2bf(v.z); r.w = f2bf(v.w);
        *((ushort4*)x1b + i) = r;
    } else {
        // ---- cvt_wt: W f32 [512][16384] -> Wt bf16 [16384][512] ----
        ushort (*lt)[65] = (ushort(*)[65])sbuf;     // [64][65], +1 pad
        const int bxl = bx - 1280;                  // 0..2047
        const int n0 = (bxl >> 3) * 64;             // 256 values
        const int d0 = (bxl & 7) * 64;              // 8 values
        #pragma unroll
        for (int it = 0; it < 4; ++it) {
            int q = it * 256 + t;
            int dl = q >> 4;
            int n4 = (q & 15) * 4;
            float4 v = *(const float4*)&W[(size_t)(d0 + dl) * NCOL + n0 + n4];
            lt[n4 + 0][dl] = f2bf(v.x);
            lt[n4 + 1][dl] = f2bf(v.y);
            lt[n4 + 2][dl] = f2bf(v.z);
            lt[n4 + 3][dl] = f2bf(v.w);
        }
        __syncthreads();
        #pragma unroll
        for (int it = 0; it < 4; ++it) {
            int q = it * 256 + t;
            int nl = q >> 4;
            int d4 = (q & 15) * 4;
            ushort4 o;
            o.x = lt[nl][d4 + 0]; o.y = lt[nl][d4 + 1];
            o.z = lt[nl][d4 + 2]; o.w = lt[nl][d4 + 3];
            *(ushort4*)&Wt[(size_t)(n0 + nl) * DIM + d0 + d4] = o;
        }
    }
}

// ---- fused GEMM: T-tile (128x128) + e-contraction with x2 -> h_part ----
// A = x1b [2048][512] bf16, Bt = Wt [16384][512] bf16 (i.e. W^T, rows = n)
// h_part[b][j][k] = sum_{e in tile j} T[b, e*32+k] * x2[b][e]
// LDS tiles XOR-swizzled: stored chunk (r,c) holds logical (r, c^((r&6)>>1)),
// via permuted GLOBAL source (LDS dest linear for global_load_lds) + same
// XOR on fragment reads (row&6 == l15&6 for all m, so XORs cancel exactly).
__global__ void gemm_fused_kernel(const ushort* __restrict__ Ab,
                                  const ushort* __restrict__ Bt,
                                  const float* __restrict__ x2,
                                  float* __restrict__ hpart) {
    __shared__ __align__(16) char smem[16384];
    ushort* As = (ushort*)smem;               // [128][32] bf16, 8KB (linear dest)
    ushort* Bs = (ushort*)(smem + 8192);      // [128][32] bf16, 8KB (linear dest)
    float*  hp = (float*)smem;                // [128][32] f32 epilogue reuse, 16KB

    const int j = blockIdx.x;                 // column tile 0..127
    const int i = blockIdx.y;                 // row tile 0..15
    const int t = threadIdx.x;
    const int lane = t & 63, wid = t >> 6;
    const int wr = wid >> 1, wc = wid & 1;    // wave grid 2x2, each 64x64
    const int row0 = i * 128, col0 = j * 128;
    const int l15 = lane & 15, lk = (lane >> 4) * 8, lh = lane >> 4;

    const int sr = t >> 2;                                // 0..63
    const int scsw = ((t & 3) ^ ((sr & 6) >> 1)) * 8;     // swizzled ushort col
    const int lksw = lk ^ ((l15 & 6) << 2);               // matching read XOR

    f32x4 acc[4][4] = {};

    for (int kt = 0; kt < DIM; kt += 32) {
        __builtin_amdgcn_global_load_lds(
            (gas_u32*)&Ab[(size_t)(row0 + sr) * DIM + kt + scsw],
            (las_u32*)&As[t * 8], 16, 0, 0);
        __builtin_amdgcn_global_load_lds(
            (gas_u32*)&Ab[(size_t)(row0 + 64 + sr) * DIM + kt + scsw],
            (las_u32*)&As[2048 + t * 8], 16, 0, 0);
        __builtin_amdgcn_global_load_lds(
            (gas_u32*)&Bt[(size_t)(col0 + sr) * DIM + kt + scsw],
            (las_u32*)&Bs[t * 8], 16, 0, 0);
        __builtin_amdgcn_global_load_lds(
            (gas_u32*)&Bt[(size_t)(col0 + 64 + sr) * DIM + kt + scsw],
            (las_u32*)&Bs[2048 + t * 8], 16, 0, 0);
        __syncthreads();
        bf16x8 af[4], bfr[4];
        #pragma unroll
        for (int m = 0; m < 4; ++m)
            af[m] = *(bf16x8*)&As[(wr * 64 + m * 16 + l15) * 32 + lksw];
        #pragma unroll
        for (int n = 0; n < 4; ++n)
            bfr[n] = *(bf16x8*)&Bs[(wc * 64 + n * 16 + l15) * 32 + lksw];
        #pragma unroll
        for (int m = 0; m < 4; ++m)
            #pragma unroll
            for (int n = 0; n < 4; ++n)
                acc[m][n] = __builtin_amdgcn_mfma_f32_16x16x32_bf16(af[m], bfr[n], acc[m][n], 0, 0, 0);
        __syncthreads();
    }

    // Epilogue: contract the 4 e-values of this tile with x2 (f32).
    // acc[m][n][reg] = T[row0 + wr*64 + m*16 + lh*4 + reg][col0 + wc*64 + n*16 + l15]
    const int e0 = j * 4 + wc * 2;            // this wave covers e0, e0+1
    if (wc == 0) {
        #pragma unroll
        for (int m = 0; m < 4; ++m) {
            #pragma unroll
            for (int reg = 0; reg < 4; ++reg) {
                int row = wr * 64 + m * 16 + lh * 4 + reg;
                float xa = x2[(size_t)(row0 + row) * DIM + e0];
                float xb = x2[(size_t)(row0 + row) * DIM + e0 + 1];
                hp[row * 32 + l15]      = acc[m][0][reg] * xa + acc[m][2][reg] * xb;
                hp[row * 32 + 16 + l15] = acc[m][1][reg] * xa + acc[m][3][reg] * xb;
            }
        }
    }
    __syncthreads();
    if (wc == 1) {
        #pragma unroll
        for (int m = 0; m < 4; ++m) {
            #pragma unroll
            for (int reg = 0; reg < 4; ++reg) {
                int row = wr * 64 + m * 16 + lh * 4 + reg;
                float xa = x2[(size_t)(row0 + row) * DIM + e0];
                float xb = x2[(size_t)(row0 + row) * DIM + e0 + 1];
                hp[row * 32 + l15]      += acc[m][0][reg] * xa + acc[m][2][reg] * xb;
                hp[row * 32 + 16 + l15] += acc[m][1][reg] * xa + acc[m][3][reg] * xb;
            }
        }
    }
    __syncthreads();
    // write h_part[b = row0+row][j][kfeat]
    #pragma unroll
    for (int q = 0; q < 4; ++q) {
        int idx = q * 1024 + t * 4;
        int row = idx >> 5, kf = idx & 31;
        *(float4*)&hpart[(size_t)(row0 + row) * (JT * KF) + j * KF + kf] = *(float4*)&hp[idx];
    }
}

// ---- final: sum h_part[b][*][*] over j, + vout + bias, relu, dot U ----
__global__ void reduce_out_kernel(const float* __restrict__ hpart,
                                  const float* __restrict__ vout,
                                  const float* __restrict__ U,
                                  const float* __restrict__ bias,
                                  float* __restrict__ out) {
    const int b = blockIdx.x;
    const int t = threadIdx.x;
    __shared__ float4 hsm[256];
    __shared__ float hk[32];

    const float* hb = hpart + (size_t)b * (JT * KF);
    float4 a4 = {0.f, 0.f, 0.f, 0.f};
    #pragma unroll
    for (int p = 0; p < 4; ++p) {
        float4 v = *(const float4*)&hb[p * 1024 + t * 4];
        a4.x += v.x; a4.y += v.y; a4.z += v.z; a4.w += v.w;
    }
    hsm[t] = a4;   // hsm[(jgroup=t>>3)*8 + (kquad=t&7)]
    __syncthreads();
    if (t < 8) {
        float4 s = {0.f, 0.f, 0.f, 0.f};
        #pragma unroll
        for (int g = 0; g < 32; ++g) {
            float4 v = hsm[g * 8 + t];
            s.x += v.x; s.y += v.y; s.z += v.z; s.w += v.w;
        }
        hk[t * 4 + 0] = s.x; hk[t * 4 + 1] = s.y;
        hk[t * 4 + 2] = s.z; hk[t * 4 + 3] = s.w;
    }
    __syncthreads();

    float val = 0.0f;
    if (t < 32) {
        float sc = hk[t] + vout[(size_t)b * KF + t] + bias[t];
        sc = fmaxf(sc, 0.0f);
        val = sc * U[t];
    }
    if (t < 64) {
        #pragma unroll
        for (int off = 16; off; off >>= 1) val += __shfl_down(val, off);
        if (t == 0) out[b] = val;
    }
}

extern "C" void kernel_launch(void* const* d_in, const int* in_sizes, int n_in,
                              void* d_out, int out_size, void* d_ws, size_t ws_size,
                              hipStream_t stream) {
    const float* x1   = (const float*)d_in[0];   // [2048][512]
    const float* x2   = (const float*)d_in[1];   // [2048][512]
    const float* W    = (const float*)d_in[2];   // [512][512][32]
    const float* V    = (const float*)d_in[3];   // [32][1024]
    const float* U    = (const float*)d_in[4];   // [32][1]
    const float* bias = (const float*)d_in[5];   // [32]
    float* out = (float*)d_out;                  // [2048]

    char* ws = (char*)d_ws;
    ushort* x1b = (ushort*)ws;                                   // 2 MB
    ushort* Wt  = (ushort*)(ws + (size_t)2 * 1024 * 1024);       // 16 MB
    float*  hp  = (float*)(ws + (size_t)18 * 1024 * 1024);       // 32 MB
    float*  vo  = (float*)(ws + (size_t)50 * 1024 * 1024);       // 256 KB

    fused_prep_kernel<<<dim3(3328), dim3(256), 0, stream>>>(x1, x2, W, V, x1b, Wt, vo);
    gemm_fused_kernel<<<dim3(JT, 16), dim3(256), 0, stream>>>(x1b, Wt, x2, hp);
    reduce_out_kernel<<<dim3(BATCH), dim3(256), 0, stream>>>(hp, vo, U, bias, out);
}